// Round 1
// baseline (612.026 us; speedup 1.0000x reference)
//
#include <hip/hip_runtime.h>
#include <math.h>

namespace {

constexpr int NEX  = 256;   // examples
constexpr int LLEN = 2048;  // series length
constexpr int TAPS = 9;     // conv taps
constexpr int PAD  = 512;   // max 4*d = 4*128
constexpr int FEATS = 8192; // features per example

// One block handles one (n, diff) pair for dilation index DI (d = D).
// 256 threads = 32 h-groups x 8 t-lanes.
template<int D, int DI>
__device__ __forceinline__ void hydra_body(
    const float* __restrict__ X, const float* __restrict__ W,
    float* __restrict__ out, float* xs, float* raw)
{
  const int n    = blockIdx.x;
  const int diff = blockIdx.y;           // 0: raw X, 1: diff(X)
  const int tid  = threadIdx.x;
  const int T    = diff ? (LLEN - 1) : LLEN;

  // Zero pad regions [0,PAD) and [PAD+LLEN, PAD+LLEN+PAD).
  for (int i = tid; i < PAD; i += 256) {
    xs[i] = 0.f;
    xs[PAD + LLEN + i] = 0.f;
  }

  const float* xrow = X + n * LLEN;
  if (diff == 0) {
    // 2048 floats = 512 float4 vectors
    for (int i = tid; i < LLEN / 4; i += 256) {
      reinterpret_cast<float4*>(xs + PAD)[i] =
          reinterpret_cast<const float4*>(xrow)[i];
    }
  } else {
    for (int i = tid; i < LLEN / 4; i += 256) {
      reinterpret_cast<float4*>(raw)[i] =
          reinterpret_cast<const float4*>(xrow)[i];
    }
    __syncthreads();
    for (int i = tid; i < LLEN - 1; i += 256) {
      xs[PAD + i] = raw[i + 1] - raw[i];
    }
    if (tid == 0) xs[PAD + LLEN - 1] = 0.f;  // last slot unused by diff branch
  }

  // Per-thread weights: h = tid>>3 fixed, 8 kernels x 9 taps = 72 floats.
  const int h  = tid >> 3;
  const int tl = tid & 7;
  float w[72];
  {
    const float4* wp = reinterpret_cast<const float4*>(
        W + ((DI * 2 + diff) * 256 + h * 8) * TAPS);
    #pragma unroll
    for (int i = 0; i < 18; ++i)
      reinterpret_cast<float4*>(w)[i] = wp[i];
  }
  __syncthreads();

  float accM[8], accN[8];
  #pragma unroll
  for (int k = 0; k < 8; ++k) { accM[k] = 0.f; accN[k] = 0.f; }

  for (int t = tl; t < T; t += 8) {
    const float* xb = xs + (PAD - 4 * D) + t;   // compile-time tap offsets j*D
    float xv[9];
    #pragma unroll
    for (int j = 0; j < 9; ++j) xv[j] = xb[j * D];

    float z[8];
    #pragma unroll
    for (int k = 0; k < 8; ++k) {
      float s = w[k * 9] * xv[0];
      #pragma unroll
      for (int j = 1; j < 9; ++j) s = fmaf(w[k * 9 + j], xv[j], s);
      z[k] = s;
    }

    const float zmax = fmaxf(fmaxf(fmaxf(z[0], z[1]), fmaxf(z[2], z[3])),
                             fmaxf(fmaxf(z[4], z[5]), fmaxf(z[6], z[7])));
    const float zmin = fminf(fminf(fminf(z[0], z[1]), fminf(z[2], z[3])),
                             fminf(fminf(z[4], z[5]), fminf(z[6], z[7])));

    // Equality-based scatter (ties are measure-zero for random fp32 data):
    #pragma unroll
    for (int k = 0; k < 8; ++k) {
      accM[k] += (z[k] == zmax) ? z[k] : 0.f;
      accN[k] += (z[k] == zmin) ? 1.f : 0.f;
    }
  }

  // Reduce across the 8 t-lanes sharing one h (butterfly keeps all lanes valid).
  #pragma unroll
  for (int m = 1; m < 8; m <<= 1) {
    #pragma unroll
    for (int k = 0; k < 8; ++k) {
      accM[k] += __shfl_xor(accM[k], m, 64);
      accN[k] += __shfl_xor(accN[k], m, 64);
    }
  }

  // Lane tl takes k==tl so the wave's stores are 64 consecutive floats.
  float vM = accM[0], vN = accN[0];
  #pragma unroll
  for (int k = 1; k < 8; ++k) {
    if (tl == k) { vM = accM[k]; vN = accN[k]; }
  }

  const int base = n * FEATS + (DI * 4 + diff * 2) * 256 + h * 8 + tl;
  out[base]       = vM > 0.f ? sqrtf(vM) : 0.f;  // count_max features
  out[base + 256] = vN > 0.f ? sqrtf(vN) : 0.f;  // count_min features
}

__global__ __launch_bounds__(256, 2) void hydra_kernel(
    const float* __restrict__ X, const float* __restrict__ W,
    float* __restrict__ out)
{
  __shared__ float xs[PAD + LLEN + PAD];  // 12 KB padded input
  __shared__ float raw[LLEN];             // 8 KB staging for diff branch
  switch (blockIdx.z) {
    case 0: hydra_body<1,   0>(X, W, out, xs, raw); break;
    case 1: hydra_body<2,   1>(X, W, out, xs, raw); break;
    case 2: hydra_body<4,   2>(X, W, out, xs, raw); break;
    case 3: hydra_body<8,   3>(X, W, out, xs, raw); break;
    case 4: hydra_body<16,  4>(X, W, out, xs, raw); break;
    case 5: hydra_body<32,  5>(X, W, out, xs, raw); break;
    case 6: hydra_body<64,  6>(X, W, out, xs, raw); break;
    case 7: hydra_body<128, 7>(X, W, out, xs, raw); break;
  }
}

} // namespace

extern "C" void kernel_launch(void* const* d_in, const int* in_sizes, int n_in,
                              void* d_out, int out_size, void* d_ws, size_t ws_size,
                              hipStream_t stream) {
  const float* X = (const float*)d_in[0];
  const float* W = (const float*)d_in[1];
  float* out = (float*)d_out;
  dim3 grid(NEX, 2, 8);
  hipLaunchKernelGGL(hydra_kernel, grid, dim3(256), 0, stream, X, W, out);
}